// Round 1
// baseline (3016.887 us; speedup 1.0000x reference)
//
#include <hip/hip_runtime.h>
#include <math.h>

#define NN 100000
#define NE 800000
#define ET (NN + NE)   /* 900000 edges incl self-loops */
#define GIN 64
#define CH 32
#define NH 4
#define NG 256
#define SLOPE 0.2f

// ---- ordered-uint encoding for float atomicMax (monotonic) ----
__device__ __forceinline__ unsigned fenc(float f) {
    unsigned u = __float_as_uint(f);
    return (u & 0x80000000u) ? ~u : (u | 0x80000000u);
}
__device__ __forceinline__ float fdec(unsigned u) {
    return (u & 0x80000000u) ? __uint_as_float(u & 0x7fffffffu) : __uint_as_float(~u);
}

// ---- node transform: XL = X@Wl+bl, XR = X@Wr+br ; W staged in LDS ----
template<int K, int M, int NPB>
__global__ void transform_kernel(const float* __restrict__ X,
                                 const float* __restrict__ Wl, const float* __restrict__ bl,
                                 const float* __restrict__ Wr, const float* __restrict__ br,
                                 float* __restrict__ XL, float* __restrict__ XR, int n)
{
    constexpr int TPN  = 2 * M;        // threads per node
    constexpr int NSUB = 256 / TPN;    // node sub-lanes per block
    __shared__ float sW[2 * K * M];
    for (int i = threadIdx.x; i < 2 * K * M; i += 256)
        sW[i] = (i < K * M) ? Wl[i] : Wr[i - K * M];
    __syncthreads();
    const int j   = threadIdx.x % TPN;
    const int sub = threadIdx.x / TPN;
    const int col = (j < M) ? j : (j - M);
    const float* Wp = sW + ((j < M) ? 0 : K * M);
    const float bias = (j < M) ? bl[col] : br[col];
    float* const out = (j < M) ? XL : XR;
    const int base = blockIdx.x * NPB;
    for (int t = sub; t < NPB; t += NSUB) {
        const int node = base + t;
        if (node >= n) break;
        const float* xrow = X + (size_t)node * K;
        float acc = bias;
        #pragma unroll
        for (int k = 0; k < K; ++k)
            acc = fmaf(xrow[k], Wp[k * M + col], acc);
        out[(size_t)node * M + col] = acc;
    }
}

// ---- pass A: attention logits + segment max ----
template<int H>
__global__ void edge_alpha_kernel(const int* __restrict__ esrc, const int* __restrict__ edst,
                                  const float* __restrict__ XL, const float* __restrict__ XR,
                                  const float* __restrict__ att,
                                  float* __restrict__ alpha, unsigned* __restrict__ amax)
{
    int tid = blockIdx.x * 256 + threadIdx.x;
    if (tid >= ET * H) return;
    int e = tid / H;
    int h = tid % H;
    int s, d;
    if (e < NE) { s = esrc[e]; d = edst[e]; } else { s = e - NE; d = s; }
    const float4* xl = (const float4*)(XL + (size_t)s * (H * CH) + h * CH);
    const float4* xr = (const float4*)(XR + (size_t)d * (H * CH) + h * CH);
    const float4* at = (const float4*)(att + h * CH);
    float acc = 0.f;
    #pragma unroll
    for (int q = 0; q < CH / 4; ++q) {
        float4 a = xl[q]; float4 b = xr[q]; float4 w = at[q];
        float v0 = a.x + b.x; v0 = v0 > 0.f ? v0 : SLOPE * v0;
        float v1 = a.y + b.y; v1 = v1 > 0.f ? v1 : SLOPE * v1;
        float v2 = a.z + b.z; v2 = v2 > 0.f ? v2 : SLOPE * v2;
        float v3 = a.w + b.w; v3 = v3 > 0.f ? v3 : SLOPE * v3;
        acc = fmaf(v0, w.x, acc);
        acc = fmaf(v1, w.y, acc);
        acc = fmaf(v2, w.z, acc);
        acc = fmaf(v3, w.w, acc);
    }
    alpha[tid] = acc;
    atomicMax(amax + (size_t)d * H + h, fenc(acc));
}

// ---- pass B: ea = exp(alpha - max), denom += ea ----
template<int H>
__global__ void edge_expsum_kernel(const int* __restrict__ edst,
                                   float* __restrict__ alpha, const unsigned* __restrict__ amax,
                                   float* __restrict__ denom)
{
    int tid = blockIdx.x * 256 + threadIdx.x;
    if (tid >= ET * H) return;
    int e = tid / H;
    int h = tid % H;
    int d = (e < NE) ? edst[e] : e - NE;
    float m = fdec(amax[(size_t)d * H + h]);
    float ea = expf(alpha[tid] - m);
    alpha[tid] = ea;
    atomicAdd(denom + (size_t)d * H + h, ea);
}

// ---- pass C: out[dst] += xl[src] * ea/denom (atomic scatter) ----
template<int H>
__global__ void edge_aggr_kernel(const int* __restrict__ esrc, const int* __restrict__ edst,
                                 const float* __restrict__ XL,
                                 const float* __restrict__ ea, const float* __restrict__ denom,
                                 float* __restrict__ out)
{
    constexpr int QPE = H * CH / 4;   // float4 quads per edge
    int tid = blockIdx.x * 256 + threadIdx.x;
    if (tid >= ET * QPE) return;
    int e = tid / QPE;
    int q = tid % QPE;
    int h = q / (CH / 4);
    int s, d;
    if (e < NE) { s = esrc[e]; d = edst[e]; } else { s = e - NE; d = s; }
    float w = ea[(size_t)e * H + h] / (denom[(size_t)d * H + h] + 1e-16f);
    const float4 xv = *(const float4*)(XL + (size_t)s * (H * CH) + q * 4);
    float* o = out + (size_t)d * (H * CH) + q * 4;
    atomicAdd(o + 0, xv.x * w);
    atomicAdd(o + 1, xv.y * w);
    atomicAdd(o + 2, xv.z * w);
    atomicAdd(o + 3, xv.w * w);
}

// ---- bias + CELU(alpha=1) in place ----
__global__ void celu_bias_kernel(float* __restrict__ h, const float* __restrict__ bias, int total)
{
    int tid = blockIdx.x * 256 + threadIdx.x;
    if (tid >= total) return;
    float v = h[tid] + bias[tid & 127];
    h[tid] = v > 0.f ? v : expm1f(v);
}

// ---- mean-pool (batch sorted: run-length accumulate, then atomic flush) ----
__global__ void pool_kernel(const float* __restrict__ h2, const float* __restrict__ bias2,
                            const int* __restrict__ batch,
                            float* __restrict__ pool, float* __restrict__ cnt)
{
    const int c    = threadIdx.x & 31;
    const int slot = threadIdx.x >> 5;     // 0..7
    const int base = blockIdx.x * 256;
    const float b = bias2[c];
    float acc = 0.f, cacc = 0.f;
    int curg = -1;
    for (int i = slot; i < 256; i += 8) {
        int node = base + i;
        if (node >= NN) break;
        int g = batch[node];
        if (g != curg) {
            if (curg >= 0) {
                atomicAdd(pool + (size_t)curg * 32 + c, acc);
                if (c == 0) atomicAdd(cnt + curg, cacc);
            }
            acc = 0.f; cacc = 0.f; curg = g;
        }
        acc += h2[(size_t)node * 32 + c] + b;
        cacc += 1.f;
    }
    if (curg >= 0) {
        atomicAdd(pool + (size_t)curg * 32 + c, acc);
        if (c == 0) atomicAdd(cnt + curg, cacc);
    }
}

// ---- per-graph head MLP: out = relu(pooled@Wh1+bh1)@Wh2 + bh2 ----
__global__ void head_kernel(const float* __restrict__ pool, const float* __restrict__ cnt,
                            const float* __restrict__ Wh1, const float* __restrict__ bh1,
                            const float* __restrict__ Wh2, const float* __restrict__ bh2,
                            float* __restrict__ out)
{
    int g = blockIdx.x;
    int c = threadIdx.x;      // 0..63
    float partial = 0.f;
    if (c < 32) {
        float invc = 1.f / fmaxf(cnt[g], 1.f);
        float acc = bh1[c];
        #pragma unroll
        for (int k = 0; k < 32; ++k)
            acc = fmaf(pool[g * 32 + k] * invc, Wh1[k * 32 + c], acc);
        float z = fmaxf(acc, 0.f);
        partial = z * Wh2[c];
    }
    #pragma unroll
    for (int off = 32; off >= 1; off >>= 1)
        partial += __shfl_down(partial, off);
    if (c == 0) out[g] = partial + bh2[0];
}

extern "C" void kernel_launch(void* const* d_in, const int* in_sizes, int n_in,
                              void* d_out, int out_size, void* d_ws, size_t ws_size,
                              hipStream_t stream)
{
    const float* x     = (const float*)d_in[0];
    const int*   ei    = (const int*)d_in[1];
    const int*   batch = (const int*)d_in[2];
    const float* Wl1   = (const float*)d_in[3];
    const float* bl1   = (const float*)d_in[4];
    const float* Wr1   = (const float*)d_in[5];
    const float* br1   = (const float*)d_in[6];
    const float* att1  = (const float*)d_in[7];
    const float* bias1 = (const float*)d_in[8];
    const float* Wl2   = (const float*)d_in[9];
    const float* bl2   = (const float*)d_in[10];
    const float* Wr2   = (const float*)d_in[11];
    const float* br2   = (const float*)d_in[12];
    const float* att2  = (const float*)d_in[13];
    const float* bias2 = (const float*)d_in[14];
    const float* Wh1   = (const float*)d_in[15];
    const float* bh1   = (const float*)d_in[16];
    const float* Wh2   = (const float*)d_in[17];
    const float* bh2   = (const float*)d_in[18];
    const int* esrc = ei;
    const int* edst = ei + NE;

    float* ws = (float*)d_ws;
    // workspace layout (floats)
    const size_t oA = 0;                       // xl1 [NN*128]; later layer-2 buffers
    const size_t oB = (size_t)NN * 128;        // xr1 [NN*128]; later alpha2/pool/cnt
    const size_t oC = (size_t)NN * 256;        // out_h1 / h1 [NN*128]
    const size_t oD = (size_t)NN * 384;        // alpha1 [ET*4]
    const size_t oE = oD + (size_t)ET * 4;     // amax1 [NN*4]
    const size_t oF = oE + (size_t)NN * 4;     // denom1 [NN*4]

    float*    xl1    = ws + oA;
    float*    xr1    = ws + oB;
    float*    h1     = ws + oC;
    float*    alpha1 = ws + oD;
    unsigned* amax1  = (unsigned*)(ws + oE);
    float*    denom1 = ws + oF;

    float*    xl2    = ws + oA;                         // NN*32
    float*    xr2    = ws + oA + (size_t)NN * 32;       // NN*32
    float*    outh2  = ws + oA + (size_t)NN * 64;       // NN*32
    unsigned* amax2  = (unsigned*)(ws + oA + (size_t)NN * 96);  // NN
    float*    denom2 = ws + oA + (size_t)NN * 97;       // NN
    float*    alpha2 = ws + oB;                         // ET
    float*    pool   = ws + oB + (size_t)ET;            // NG*32
    float*    cnt    = ws + oB + (size_t)ET + NG * 32;  // NG

    // zero out_h1 + alpha1 + amax1 + denom1 (one contiguous region)
    hipMemsetAsync(ws + oC, 0,
                   ((size_t)NN * 128 + (size_t)ET * 4 + (size_t)NN * 8) * sizeof(float),
                   stream);

    // ---- layer 1 ----
    transform_kernel<64, 128, 32><<<(NN + 31) / 32, 256, 0, stream>>>(
        x, Wl1, bl1, Wr1, br1, xl1, xr1, NN);
    {
        int total = ET * NH;
        edge_alpha_kernel<NH><<<(total + 255) / 256, 256, 0, stream>>>(
            esrc, edst, xl1, xr1, att1, alpha1, amax1);
        edge_expsum_kernel<NH><<<(total + 255) / 256, 256, 0, stream>>>(
            edst, alpha1, amax1, denom1);
        int ta = ET * 32;
        edge_aggr_kernel<NH><<<(ta + 255) / 256, 256, 0, stream>>>(
            esrc, edst, xl1, alpha1, denom1, h1);
    }
    celu_bias_kernel<<<((NN * 128) + 255) / 256, 256, 0, stream>>>(h1, bias1, NN * 128);

    // zero layer-2 accumulators (outh2+amax2+denom2 contiguous; pool+cnt contiguous)
    hipMemsetAsync(ws + oA + (size_t)NN * 64, 0, (size_t)NN * 34 * sizeof(float), stream);
    hipMemsetAsync(pool, 0, (size_t)NG * 33 * sizeof(float), stream);

    // ---- layer 2 ----
    transform_kernel<128, 32, 32><<<(NN + 31) / 32, 256, 0, stream>>>(
        h1, Wl2, bl2, Wr2, br2, xl2, xr2, NN);
    {
        edge_alpha_kernel<1><<<(ET + 255) / 256, 256, 0, stream>>>(
            esrc, edst, xl2, xr2, att2, alpha2, amax2);
        edge_expsum_kernel<1><<<(ET + 255) / 256, 256, 0, stream>>>(
            edst, alpha2, amax2, denom2);
        int ta = ET * 8;
        edge_aggr_kernel<1><<<(ta + 255) / 256, 256, 0, stream>>>(
            esrc, edst, xl2, alpha2, denom2, outh2);
    }

    // ---- pool + head ----
    pool_kernel<<<(NN + 255) / 256, 256, 0, stream>>>(outh2, bias2, batch, pool, cnt);
    head_kernel<<<NG, 64, 0, stream>>>(pool, cnt, Wh1, bh1, Wh2, bh2, (float*)d_out);
}

// Round 2
// 1040.730 us; speedup vs baseline: 2.8988x; 2.8988x over previous
//
#include <hip/hip_runtime.h>
#include <math.h>

#define NN 100000
#define NE 800000
#define ET (NN + NE)   /* 900000 edges incl self-loops */
#define GIN 64
#define CH 32
#define NH 4
#define NG 256
#define SLOPE 0.2f
#define NB1 ((NN + 255) / 256)   /* 391 scan blocks */

// ---- node transform: XL = X@Wl+bl, XR = X@Wr+br ; W staged in LDS ----
template<int K, int M, int NPB>
__global__ void transform_kernel(const float* __restrict__ X,
                                 const float* __restrict__ Wl, const float* __restrict__ bl,
                                 const float* __restrict__ Wr, const float* __restrict__ br,
                                 float* __restrict__ XL, float* __restrict__ XR, int n)
{
    constexpr int TPN  = 2 * M;        // threads per node
    constexpr int NSUB = 256 / TPN;    // node sub-lanes per block
    __shared__ float sW[2 * K * M];
    for (int i = threadIdx.x; i < 2 * K * M; i += 256)
        sW[i] = (i < K * M) ? Wl[i] : Wr[i - K * M];
    __syncthreads();
    const int j   = threadIdx.x % TPN;
    const int sub = threadIdx.x / TPN;
    const int col = (j < M) ? j : (j - M);
    const float* Wp = sW + ((j < M) ? 0 : K * M);
    const float bias = (j < M) ? bl[col] : br[col];
    float* const out = (j < M) ? XL : XR;
    const int base = blockIdx.x * NPB;
    for (int t = sub; t < NPB; t += NSUB) {
        const int node = base + t;
        if (node >= n) break;
        const float* xrow = X + (size_t)node * K;
        float acc = bias;
        #pragma unroll
        for (int k = 0; k < K; ++k)
            acc = fmaf(xrow[k], Wp[k * M + col], acc);
        out[(size_t)node * M + col] = acc;
    }
}

// ---- CSR build: histogram of dst ----
__global__ void hist_kernel(const int* __restrict__ edst, int* __restrict__ deg)
{
    int e = blockIdx.x * 256 + threadIdx.x;
    if (e >= ET) return;
    int d = (e < NE) ? edst[e] : (e - NE);
    atomicAdd(deg + d, 1);
}

// ---- 3-kernel exclusive scan: rowstart[i] = sum(deg[0..i-1]) ----
__global__ void scan1_kernel(const int* __restrict__ deg, int* __restrict__ rowstart,
                             int* __restrict__ bsum)
{
    __shared__ int lds[256];
    int t = threadIdx.x, idx = blockIdx.x * 256 + t;
    int v = (idx < NN) ? deg[idx] : 0;
    lds[t] = v;
    __syncthreads();
    #pragma unroll
    for (int off = 1; off < 256; off <<= 1) {
        int add = (t >= off) ? lds[t - off] : 0;
        __syncthreads();
        lds[t] += add;
        __syncthreads();
    }
    if (idx < NN) rowstart[idx + 1] = lds[t];   // inclusive, block-local
    if (t == 255) bsum[blockIdx.x] = lds[255];
}

__global__ void scan2_kernel(int* __restrict__ bsum)   // exclusive scan of NB1 sums
{
    __shared__ int lds[512];
    int t = threadIdx.x;
    int v = (t < NB1) ? bsum[t] : 0;
    lds[t] = v;
    __syncthreads();
    #pragma unroll
    for (int off = 1; off < 512; off <<= 1) {
        int add = (t >= off) ? lds[t - off] : 0;
        __syncthreads();
        lds[t] += add;
        __syncthreads();
    }
    if (t < NB1) bsum[t] = lds[t] - v;
}

__global__ void scan3_kernel(int* __restrict__ rowstart, const int* __restrict__ bsum)
{
    int idx = blockIdx.x * 256 + threadIdx.x;
    if (idx == 0) rowstart[0] = 0;
    if (idx < NN) rowstart[idx + 1] += bsum[blockIdx.x];
}

// ---- CSR scatter: fill src ids per dst row ----
__global__ void scatter_kernel(const int* __restrict__ esrc, const int* __restrict__ edst,
                               const int* __restrict__ rowstart,
                               int* __restrict__ cursor, int* __restrict__ csr_src)
{
    int e = blockIdx.x * 256 + threadIdx.x;
    if (e >= ET) return;
    int s, d;
    if (e < NE) { s = esrc[e]; d = edst[e]; } else { s = e - NE; d = s; }
    int pos = rowstart[d] + atomicAdd(cursor + d, 1);
    csr_src[pos] = s;
}

// ---- layer 1 fused GATv2 (H=4, C=32): one wave per dst node, online softmax ----
// lane covers channels (2*lane, 2*lane+1); head = lane>>4; epilogue adds bias1 + CELU.
__global__ void gat1_kernel(const int* __restrict__ rowstart, const int* __restrict__ csr_src,
                            const float* __restrict__ XL, const float* __restrict__ XR,
                            const float* __restrict__ att, const float* __restrict__ bias,
                            float* __restrict__ H1)
{
    int node = blockIdx.x * 4 + (threadIdx.x >> 6);
    if (node >= NN) return;
    const int lane = threadIdx.x & 63;
    const int c0 = lane * 2;
    const float2 xr = *(const float2*)(XR + (size_t)node * 128 + c0);
    const float2 at = *(const float2*)(att + c0);
    const int beg = rowstart[node], end = rowstart[node + 1];
    float m = -INFINITY, ssum = 0.f, acc0 = 0.f, acc1 = 0.f;
    for (int i = beg; i < end; ++i) {
        const int s = csr_src[i];
        const float2 xl = *(const float2*)(XL + (size_t)s * 128 + c0);
        float v0 = xl.x + xr.x; v0 = v0 > 0.f ? v0 : SLOPE * v0;
        float v1 = xl.y + xr.y; v1 = v1 > 0.f ? v1 : SLOPE * v1;
        float p = fmaf(v0, at.x, v1 * at.y);
        p += __shfl_xor(p, 1);
        p += __shfl_xor(p, 2);
        p += __shfl_xor(p, 4);
        p += __shfl_xor(p, 8);       // p = alpha for head (lane>>4)
        float ea;
        if (p > m) {
            float sc = expf(m - p);  // exp(-inf)=0 on first edge: zeroes nothing
            ssum *= sc; acc0 *= sc; acc1 *= sc;
            m = p; ea = 1.f;
        } else {
            ea = expf(p - m);
        }
        ssum += ea;
        acc0 = fmaf(ea, xl.x, acc0);
        acc1 = fmaf(ea, xl.y, acc1);
    }
    const float inv = 1.f / (ssum + 1e-16f);
    float o0 = fmaf(acc0, inv, 0.f) + bias[c0];
    float o1 = fmaf(acc1, inv, 0.f) + bias[c0 + 1];
    o0 = o0 > 0.f ? o0 : expm1f(o0);
    o1 = o1 > 0.f ? o1 : expm1f(o1);
    *(float2*)(H1 + (size_t)node * 128 + c0) = make_float2(o0, o1);
}

// ---- layer 2 fused GATv2 (H=1, C=32): one half-wave per dst node ----
__global__ void gat2_kernel(const int* __restrict__ rowstart, const int* __restrict__ csr_src,
                            const float* __restrict__ XL, const float* __restrict__ XR,
                            const float* __restrict__ att,
                            float* __restrict__ H2)
{
    int node = blockIdx.x * 8 + (threadIdx.x >> 5);
    if (node >= NN) return;
    const int c = threadIdx.x & 31;
    const float xr = XR[(size_t)node * 32 + c];
    const float at = att[c];
    const int beg = rowstart[node], end = rowstart[node + 1];
    float m = -INFINITY, ssum = 0.f, acc = 0.f;
    for (int i = beg; i < end; ++i) {
        const int s = csr_src[i];
        const float xl = XL[(size_t)s * 32 + c];
        float v = xl + xr; v = v > 0.f ? v : SLOPE * v;
        float p = v * at;
        p += __shfl_xor(p, 1);
        p += __shfl_xor(p, 2);
        p += __shfl_xor(p, 4);
        p += __shfl_xor(p, 8);
        p += __shfl_xor(p, 16);      // alpha for this node (32-lane reduce)
        float ea;
        if (p > m) {
            float sc = expf(m - p);
            ssum *= sc; acc *= sc;
            m = p; ea = 1.f;
        } else {
            ea = expf(p - m);
        }
        ssum += ea;
        acc = fmaf(ea, xl, acc);
    }
    H2[(size_t)node * 32 + c] = acc / (ssum + 1e-16f);
}

// ---- mean-pool (batch sorted: run-length accumulate, then atomic flush) ----
__global__ void pool_kernel(const float* __restrict__ h2, const float* __restrict__ bias2,
                            const int* __restrict__ batch,
                            float* __restrict__ pool, float* __restrict__ cnt)
{
    const int c    = threadIdx.x & 31;
    const int slot = threadIdx.x >> 5;     // 0..7
    const int base = blockIdx.x * 256;
    const float b = bias2[c];
    float acc = 0.f, cacc = 0.f;
    int curg = -1;
    for (int i = slot; i < 256; i += 8) {
        int node = base + i;
        if (node >= NN) break;
        int g = batch[node];
        if (g != curg) {
            if (curg >= 0) {
                atomicAdd(pool + (size_t)curg * 32 + c, acc);
                if (c == 0) atomicAdd(cnt + curg, cacc);
            }
            acc = 0.f; cacc = 0.f; curg = g;
        }
        acc += h2[(size_t)node * 32 + c] + b;
        cacc += 1.f;
    }
    if (curg >= 0) {
        atomicAdd(pool + (size_t)curg * 32 + c, acc);
        if (c == 0) atomicAdd(cnt + curg, cacc);
    }
}

// ---- per-graph head MLP: out = relu(pooled@Wh1+bh1)@Wh2 + bh2 ----
__global__ void head_kernel(const float* __restrict__ pool, const float* __restrict__ cnt,
                            const float* __restrict__ Wh1, const float* __restrict__ bh1,
                            const float* __restrict__ Wh2, const float* __restrict__ bh2,
                            float* __restrict__ out)
{
    int g = blockIdx.x;
    int c = threadIdx.x;      // 0..63
    float partial = 0.f;
    if (c < 32) {
        float invc = 1.f / fmaxf(cnt[g], 1.f);
        float acc = bh1[c];
        #pragma unroll
        for (int k = 0; k < 32; ++k)
            acc = fmaf(pool[g * 32 + k] * invc, Wh1[k * 32 + c], acc);
        float z = fmaxf(acc, 0.f);
        partial = z * Wh2[c];
    }
    #pragma unroll
    for (int off = 32; off >= 1; off >>= 1)
        partial += __shfl_down(partial, off);
    if (c == 0) out[g] = partial + bh2[0];
}

extern "C" void kernel_launch(void* const* d_in, const int* in_sizes, int n_in,
                              void* d_out, int out_size, void* d_ws, size_t ws_size,
                              hipStream_t stream)
{
    const float* x     = (const float*)d_in[0];
    const int*   ei    = (const int*)d_in[1];
    const int*   batch = (const int*)d_in[2];
    const float* Wl1   = (const float*)d_in[3];
    const float* bl1   = (const float*)d_in[4];
    const float* Wr1   = (const float*)d_in[5];
    const float* br1   = (const float*)d_in[6];
    const float* att1  = (const float*)d_in[7];
    const float* bias1 = (const float*)d_in[8];
    const float* Wl2   = (const float*)d_in[9];
    const float* bl2   = (const float*)d_in[10];
    const float* Wr2   = (const float*)d_in[11];
    const float* br2   = (const float*)d_in[12];
    const float* att2  = (const float*)d_in[13];
    const float* bias2 = (const float*)d_in[14];
    const float* Wh1   = (const float*)d_in[15];
    const float* bh1   = (const float*)d_in[16];
    const float* Wh2   = (const float*)d_in[17];
    const float* bh2   = (const float*)d_in[18];
    const int* esrc = ei;
    const int* edst = ei + NE;

    // ---- workspace layout ----
    float* ws  = (float*)d_ws;
    float* xl1 = ws;                            // NN*128
    float* xr1 = ws + (size_t)NN * 128;         // NN*128; h1 aliases (per-row RAW only)
    float* h1  = xr1;
    float* xl2 = ws + (size_t)NN * 256;         // NN*32
    float* xr2 = xl2 + (size_t)NN * 32;         // NN*32; h2 aliases
    float* h2  = xr2;
    float* pool = xr2 + (size_t)NN * 32;        // NG*32
    float* cnt  = pool + (size_t)NG * 32;       // NG
    int* ib       = (int*)(cnt + NG);
    int* deg      = ib;                         // NN (reused as cursor)
    int* rowstart = ib + NN;                    // NN+1
    int* bsum     = ib + 2 * NN + 1;            // 512
    int* csr_src  = ib + 2 * NN + 1 + 512;      // ET

    // ---- CSR build ----
    hipMemsetAsync(deg, 0, NN * sizeof(int), stream);
    hipMemsetAsync(pool, 0, (size_t)(NG * 33) * sizeof(float), stream);
    hist_kernel<<<(ET + 255) / 256, 256, 0, stream>>>(edst, deg);
    scan1_kernel<<<NB1, 256, 0, stream>>>(deg, rowstart, bsum);
    scan2_kernel<<<1, 512, 0, stream>>>(bsum);
    scan3_kernel<<<NB1, 256, 0, stream>>>(rowstart, bsum);
    hipMemsetAsync(deg, 0, NN * sizeof(int), stream);   // -> cursor
    scatter_kernel<<<(ET + 255) / 256, 256, 0, stream>>>(esrc, edst, rowstart, deg, csr_src);

    // ---- layer 1 ----
    transform_kernel<64, 128, 32><<<(NN + 31) / 32, 256, 0, stream>>>(
        x, Wl1, bl1, Wr1, br1, xl1, xr1, NN);
    gat1_kernel<<<(NN + 3) / 4, 256, 0, stream>>>(
        rowstart, csr_src, xl1, xr1, att1, bias1, h1);

    // ---- layer 2 ----
    transform_kernel<128, 32, 32><<<(NN + 31) / 32, 256, 0, stream>>>(
        h1, Wl2, bl2, Wr2, br2, xl2, xr2, NN);
    gat2_kernel<<<(NN + 7) / 8, 256, 0, stream>>>(
        rowstart, csr_src, xl2, xr2, att2, h2);

    // ---- pool + head ----
    pool_kernel<<<(NN + 255) / 256, 256, 0, stream>>>(h2, bias2, batch, pool, cnt);
    head_kernel<<<NG, 64, 0, stream>>>(pool, cnt, Wh1, bh1, Wh2, bh2, (float*)d_out);
}